// Round 4
// baseline (83.767 us; speedup 1.0000x reference)
//
#include <hip/hip_runtime.h>
#include <hip/hip_fp16.h>
#include <math.h>

#define N_ATOMS 512
#define N_MOL   16
#define HIDDEN  128
#define FILTERS 128
#define NUM_RBF 50
#define CUTOFF  10.0f
#define N_LAYERS 3

#define KBINS  1024          // lerp bins over [0, CUTOFF]
#define TROWS  (KBINS + 2)   // bins evaluated: 0..1025 (>=1024 are zero rows)
#define PROWS  (KBINS + 1)   // pair rows 0..1024; row k = {phi_k, phi_{k+1}} as 2x bf16
#define TB     32            // bins per table block
#define TBLK   ((TROWS + TB - 1) / TB)   // 33 table blocks per layer
#define EMB_BLOCKS 64

__device__ __forceinline__ unsigned short f2bf(float v) {
    unsigned u = __float_as_uint(v);
    u += 0x7fffu + ((u >> 16) & 1u);          // round-to-nearest-even
    return (unsigned short)(u >> 16);
}

// ============ front kernel: embedding+xj0 ∥ filter tables ============
// All weight matrices staged to LDS as fp16 via independent float4 loads
// (kills the serial cold-HBM dependent-load chain that cost 42 us in R3).
__global__ void __launch_bounds__(256) k_front(
        const int* __restrict__ an, const float* __restrict__ emb,
        const float* __restrict__ d1w, const float* __restrict__ d1b,
        const float* __restrict__ fw1, const float* __restrict__ fb1,
        const float* __restrict__ fw2, const float* __restrict__ fb2,
        float* __restrict__ x, float* __restrict__ xj,
        unsigned short* __restrict__ tab) {
    __shared__ __align__(16) char smem[62 * 1024];
    int bid = blockIdx.x, t = threadIdx.x;

    if (bid < EMB_BLOCKS) {
        // ---------- embedding gather + xj0 = x @ d1w[0] + d1b[0], 8 atoms ----------
        float*  s_row = (float*)smem;                 // 8*128*4 = 4 KB
        __half* s_w   = (__half*)(smem + 4096);       // 128*128*2 = 32 KB
        const float4* wv = (const float4*)d1w;
        for (int idx = t; idx < HIDDEN * FILTERS / 4; idx += 256) {
            float4 v = wv[idx];
            __half2* dst = (__half2*)(s_w + idx * 4);
            dst[0] = __floats2half2_rn(v.x, v.y);
            dst[1] = __floats2half2_rn(v.z, v.w);
        }
        int i0 = bid * 8;
        for (int idx = t; idx < 8 * HIDDEN; idx += 256) {
            int a = idx >> 7, c2 = idx & 127;
            float v = emb[an[i0 + a] * HIDDEN + c2];
            s_row[a * HIDDEN + c2] = v;
            x[(i0 + a) * HIDDEN + c2] = v;
        }
        __syncthreads();
        int c = t & 127, g = t >> 7;                  // g: atoms g*4 .. g*4+3
        float acc[4];
        float bv = d1b[c];
        #pragma unroll
        for (int aa = 0; aa < 4; aa++) acc[aa] = bv;
        #pragma unroll 4
        for (int h = 0; h < HIDDEN; h++) {
            float w = __half2float(s_w[h * FILTERS + c]);
            #pragma unroll
            for (int aa = 0; aa < 4; aa++)
                acc[aa] = fmaf(s_row[(g * 4 + aa) * HIDDEN + h], w, acc[aa]);
        }
        #pragma unroll
        for (int aa = 0; aa < 4; aa++) xj[(i0 + g * 4 + aa) * FILTERS + c] = acc[aa];
    } else {
        // ---------- filter table: 32 bins/block, weights in fp16 LDS ----------
        int tb = bid - EMB_BLOCKS;
        int l  = tb / TBLK, bx = tb % TBLK;
        int bin0 = bx * TB;
        __half* s_w1h = (__half*)smem;                         // 50*128*2  = 12800 B
        __half* s_w2h = (__half*)(smem + 12800);               // 128*128*2 = 32768 B
        float*  s_rbf = (float*)(smem + 12800 + 32768);        // [32][50] (phase 1)
        float*  s_h   = (float*)(smem + 12800 + 32768);        // [32][128] (phase 2, union)

        const float4* w1v = (const float4*)(fw1 + (size_t)l * NUM_RBF * FILTERS);
        for (int idx = t; idx < NUM_RBF * FILTERS / 4; idx += 256) {
            float4 v = w1v[idx];
            __half2* dst = (__half2*)(s_w1h + idx * 4);
            dst[0] = __floats2half2_rn(v.x, v.y);
            dst[1] = __floats2half2_rn(v.z, v.w);
        }
        const float4* w2v = (const float4*)(fw2 + (size_t)l * FILTERS * FILTERS);
        for (int idx = t; idx < FILTERS * FILTERS / 4; idx += 256) {
            float4 v = w2v[idx];
            __half2* dst = (__half2*)(s_w2h + idx * 4);
            dst[0] = __floats2half2_rn(v.x, v.y);
            dst[1] = __floats2half2_rn(v.z, v.w);
        }
        for (int idx = t; idx < TB * NUM_RBF; idx += 256) {
            int lb = idx / NUM_RBF, r = idx % NUM_RBF;
            float dd = (bin0 + lb) * (CUTOFF / (float)KBINS);
            float cr = r * (CUTOFF / (float)(NUM_RBF - 1));
            float xx = dd - cr;
            s_rbf[lb * NUM_RBF + r] = expf(-xx * xx * 12.5f);   // 1/(2*w^2), w = 0.2
        }
        __syncthreads();
        int c = t & 127, sub = t >> 7;               // thread owns bins 2*bb+sub
        float h[16];
        float bv1 = fb1[l * FILTERS + c];
        #pragma unroll
        for (int bb = 0; bb < 16; bb++) h[bb] = bv1;
        for (int r = 0; r < NUM_RBF; r++) {
            float w = __half2float(s_w1h[r * FILTERS + c]);
            #pragma unroll
            for (int bb = 0; bb < 16; bb++)
                h[bb] = fmaf(s_rbf[(2 * bb + sub) * NUM_RBF + r], w, h[bb]);
        }
        __syncthreads();                              // done with s_rbf
        #pragma unroll
        for (int bb = 0; bb < 16; bb++) {
            float a = h[bb];
            s_h[(2 * bb + sub) * FILTERS + c] = a / (1.f + expf(-a));   // silu
        }
        __syncthreads();
        float o[16];
        float bv2 = fb2[l * FILTERS + c];
        #pragma unroll
        for (int bb = 0; bb < 16; bb++) o[bb] = bv2;
        #pragma unroll 2
        for (int hh = 0; hh < FILTERS; hh++) {
            float w = __half2float(s_w2h[hh * FILTERS + c]);
            #pragma unroll
            for (int bb = 0; bb < 16; bb++)
                o[bb] = fmaf(s_h[(2 * bb + sub) * FILTERS + hh], w, o[bb]);
        }
        size_t base = (size_t)l * PROWS * FILTERS * 2;
        #pragma unroll
        for (int bb = 0; bb < 16; bb++) {
            int bin = bin0 + 2 * bb + sub;
            float dd = bin * (CUTOFF / (float)KBINS);
            float env = (bin >= KBINS) ? 0.f : 0.5f * (cosf(dd * (3.14159265358979f / CUTOFF)) + 1.f);
            unsigned short pb = f2bf(o[bb] * env);
            if (bin <= KBINS)               tab[base + ((size_t)bin * FILTERS + c) * 2 + 0] = pb;
            if (bin >= 1 && bin <= KBINS + 1) tab[base + ((size_t)(bin - 1) * FILTERS + c) * 2 + 1] = pb;
        }
    }
}

// ======== fused layer: (kw build for l=0) + agg + x update + next xj; one j per block ========
template<int FIRST, int LAST>
__global__ void __launch_bounds__(512) k_layer(const float* __restrict__ pos,
        float2* __restrict__ kw, const unsigned int* __restrict__ tab,
        const float* __restrict__ xj_in, float* __restrict__ x,
        const float* __restrict__ w2, const float* __restrict__ b2,
        const float* __restrict__ w1n, const float* __restrict__ b1n,
        float* __restrict__ xj_out) {
    int j = blockIdx.x;
    int t = threadIdx.x, f = t & 127, q = t >> 7;    // q in 0..3: i-quarter
    __shared__ float2 s_kw[N_ATOMS];
    __shared__ float  s_red[4][FILTERS];
    __shared__ float  s_agg[FILTERS];
    __shared__ float  s_xn[HIDDEN];
    __shared__ float  s_pos[FIRST ? N_ATOMS * 3 : 1];
    if (FIRST) {
        for (int idx = t; idx < N_ATOMS * 3; idx += 512) s_pos[idx] = pos[idx];
        __syncthreads();
        float pjx = s_pos[j*3+0], pjy = s_pos[j*3+1], pjz = s_pos[j*3+2];
        float dx = s_pos[t*3+0] - pjx;
        float dy = s_pos[t*3+1] - pjy;
        float dz = s_pos[t*3+2] - pjz;
        float d  = sqrtf(dx*dx + dy*dy + dz*dz);
        int   k; float w;
        if (t == j || d >= CUTOFF) { k = KBINS; w = 0.f; }   // all-zero pair row
        else {
            float tt = d * ((float)KBINS / CUTOFF);
            k = (int)tt;
            if (k > KBINS - 1) k = KBINS - 1;
            w = tt - (float)k;
        }
        float2 kv = make_float2(w, __int_as_float(k));
        s_kw[t] = kv;
        kw[(size_t)j * N_ATOMS + t] = kv;
        __syncthreads();
    } else {
        s_kw[t] = kw[(size_t)j * N_ATOMS + t];
        __syncthreads();
    }
    // ---- aggregation: each quarter sums 128 source atoms, 4 accumulators ----
    float acc0 = 0.f, acc1 = 0.f, acc2 = 0.f, acc3 = 0.f;
    int i0 = q * 128;
    #pragma unroll 2
    for (int ii = 0; ii < 128; ii += 4) {
        float2 kv0 = s_kw[i0 + ii];
        float2 kv1 = s_kw[i0 + ii + 1];
        float2 kv2 = s_kw[i0 + ii + 2];
        float2 kv3 = s_kw[i0 + ii + 3];
        unsigned int p0 = tab[(size_t)__float_as_int(kv0.y) * FILTERS + f];
        unsigned int p1 = tab[(size_t)__float_as_int(kv1.y) * FILTERS + f];
        unsigned int p2 = tab[(size_t)__float_as_int(kv2.y) * FILTERS + f];
        unsigned int p3 = tab[(size_t)__float_as_int(kv3.y) * FILTERS + f];
        float xv0 = xj_in[(size_t)(i0 + ii    )*FILTERS + f];
        float xv1 = xj_in[(size_t)(i0 + ii + 1)*FILTERS + f];
        float xv2 = xj_in[(size_t)(i0 + ii + 2)*FILTERS + f];
        float xv3 = xj_in[(size_t)(i0 + ii + 3)*FILTERS + f];
        float lo0 = __uint_as_float(p0 << 16), hi0 = __uint_as_float(p0 & 0xffff0000u);
        float lo1 = __uint_as_float(p1 << 16), hi1 = __uint_as_float(p1 & 0xffff0000u);
        float lo2 = __uint_as_float(p2 << 16), hi2 = __uint_as_float(p2 & 0xffff0000u);
        float lo3 = __uint_as_float(p3 << 16), hi3 = __uint_as_float(p3 & 0xffff0000u);
        acc0 = fmaf(xv0, fmaf(kv0.x, hi0 - lo0, lo0), acc0);
        acc1 = fmaf(xv1, fmaf(kv1.x, hi1 - lo1, lo1), acc1);
        acc2 = fmaf(xv2, fmaf(kv2.x, hi2 - lo2, lo2), acc2);
        acc3 = fmaf(xv3, fmaf(kv3.x, hi3 - lo3, lo3), acc3);
    }
    s_red[q][f] = (acc0 + acc1) + (acc2 + acc3);
    __syncthreads();
    if (q == 0) s_agg[f] = s_red[0][f] + s_red[1][f] + s_red[2][f] + s_red[3][f];
    __syncthreads();
    // ---- x update: split the 128-term dot over quarters (32 each) ----
    float v = 0.f;
    int ff0 = q * 32;
    #pragma unroll 8
    for (int ff = ff0; ff < ff0 + 32; ff++) v = fmaf(s_agg[ff], w2[ff*HIDDEN + f], v);
    s_red[q][f] = v;
    __syncthreads();
    if (q == 0) {
        float xnew = x[j*HIDDEN + f] + b2[f] + s_red[0][f] + s_red[1][f] + s_red[2][f] + s_red[3][f];
        x[j*HIDDEN + f] = xnew;
        s_xn[f] = xnew;
    }
    __syncthreads();
    if (!LAST) {
        float a2 = 0.f;
        int h0 = q * 32;
        #pragma unroll 8
        for (int hh = h0; hh < h0 + 32; hh++) a2 = fmaf(s_xn[hh], w1n[hh*FILTERS + f], a2);
        s_red[q][f] = a2;
        __syncthreads();
        if (q == 0) xj_out[j*FILTERS + f] = b1n[f] + s_red[0][f] + s_red[1][f] + s_red[2][f] + s_red[3][f];
    }
}

// ============ molecule pool + output MLP (binary search on sorted batch) ============
__device__ __forceinline__ int lbound(const int* __restrict__ b, int n, int v) {
    int lo = 0, hi = n;
    while (lo < hi) { int mid = (lo + hi) >> 1; if (b[mid] < v) lo = mid + 1; else hi = mid; }
    return lo;
}

__global__ void __launch_bounds__(128) k_pool(const float* __restrict__ x,
        const int* __restrict__ batch, const float* __restrict__ ow1,
        const float* __restrict__ ob1, const float* __restrict__ ow2,
        const float* __restrict__ ob2, float* __restrict__ out) {
    int m = blockIdx.x, t = threadIdx.x;
    int lo = lbound(batch, N_ATOMS, m);
    int hi = lbound(batch, N_ATOMS, m + 1);
    float s = 0.f;
    for (int i = lo; i < hi; i++) s += x[i*HIDDEN + t];
    int cnt = hi - lo;
    float mol = s / (float)(cnt > 0 ? cnt : 1);
    __shared__ float s_mol[HIDDEN];
    __shared__ float s_h[HIDDEN/2];
    s_mol[t] = mol;
    __syncthreads();
    if (t < HIDDEN/2) {
        float a = ob1[t];
        for (int h = 0; h < HIDDEN; h++) a = fmaf(s_mol[h], ow1[h*(HIDDEN/2) + t], a);
        s_h[t] = a / (1.f + expf(-a));
    }
    __syncthreads();
    if (t == 0) {
        float a = ob2[0];
        for (int h = 0; h < HIDDEN/2; h++) a = fmaf(s_h[h], ow2[h], a);
        out[m] = a;
    }
}

extern "C" void kernel_launch(void* const* d_in, const int* in_sizes, int n_in,
                              void* d_out, int out_size, void* d_ws, size_t ws_size,
                              hipStream_t stream) {
    const int*   an    = (const int*)  d_in[0];
    const float* pos   = (const float*)d_in[1];
    const int*   batch = (const int*)  d_in[2];
    const float* emb   = (const float*)d_in[3];
    const float* fw1   = (const float*)d_in[4];
    const float* fb1   = (const float*)d_in[5];
    const float* fw2   = (const float*)d_in[6];
    const float* fb2   = (const float*)d_in[7];
    const float* d1w   = (const float*)d_in[8];
    const float* d1b   = (const float*)d_in[9];
    const float* d2w   = (const float*)d_in[10];
    const float* d2b   = (const float*)d_in[11];
    const float* ow1   = (const float*)d_in[12];
    const float* ob1   = (const float*)d_in[13];
    const float* ow2   = (const float*)d_in[14];
    const float* ob2   = (const float*)d_in[15];
    float* out = (float*)d_out;

    float*          ws   = (float*)d_ws;
    float2*         kw   = (float2*)ws;                              // 2 MB
    float*          x    = (float*)(kw + (size_t)N_ATOMS*N_ATOMS);   // 256 KB
    float*          xjA  = x   + N_ATOMS*HIDDEN;                     // 256 KB
    float*          xjB  = xjA + N_ATOMS*FILTERS;                    // 256 KB
    unsigned short* tab  = (unsigned short*)(xjB + N_ATOMS*FILTERS); // 1.575 MB

    k_front<<<EMB_BLOCKS + N_LAYERS*TBLK, 256, 0, stream>>>(
        an, emb, d1w, d1b, fw1, fb1, fw2, fb2, x, xjA, tab);

    const unsigned int* t0 = (const unsigned int*)(tab + (size_t)0 * PROWS * FILTERS * 2);
    const unsigned int* t1 = (const unsigned int*)(tab + (size_t)1 * PROWS * FILTERS * 2);
    const unsigned int* t2 = (const unsigned int*)(tab + (size_t)2 * PROWS * FILTERS * 2);

    k_layer<1,0><<<N_ATOMS, 512, 0, stream>>>(pos, kw, t0, xjA, x,
        d2w + (size_t)0*FILTERS*HIDDEN, d2b + (size_t)0*HIDDEN,
        d1w + (size_t)1*HIDDEN*FILTERS, d1b + (size_t)1*FILTERS, xjB);
    k_layer<0,0><<<N_ATOMS, 512, 0, stream>>>(pos, kw, t1, xjB, x,
        d2w + (size_t)1*FILTERS*HIDDEN, d2b + (size_t)1*HIDDEN,
        d1w + (size_t)2*HIDDEN*FILTERS, d1b + (size_t)2*FILTERS, xjA);
    k_layer<0,1><<<N_ATOMS, 512, 0, stream>>>(pos, kw, t2, xjA, x,
        d2w + (size_t)2*FILTERS*HIDDEN, d2b + (size_t)2*HIDDEN,
        d1w, d1b, xjB);

    k_pool<<<N_MOL, 128, 0, stream>>>(x, batch, ow1, ob1, ow2, ob2, out);
}

// Round 5
// 73.580 us; speedup vs baseline: 1.1384x; 1.1384x over previous
//
#include <hip/hip_runtime.h>
#include <math.h>

#define N_ATOMS 512
#define N_MOL   16
#define HIDDEN  128
#define FILTERS 128
#define NUM_RBF 50
#define CUTOFF  10.0f
#define N_LAYERS 3

#define KBINS  1024          // lerp bins over [0, CUTOFF]
#define PROWS  (KBINS + 1)   // pair rows 0..1024; row k = {phi_k, phi_{k+1}} as 2x bf16
#define TB     32            // bins per table block
#define TBLK   33            // table blocks per layer (covers 1056 >= 1026 bins)
#define EMB_BLOCKS 16        // 32 atoms per block

__device__ __forceinline__ unsigned short f2bf(float v) {
    unsigned u = __float_as_uint(v);
    u += 0x7fffu + ((u >> 16) & 1u);          // round-to-nearest-even
    return (unsigned short)(u >> 16);
}
__device__ __forceinline__ float bf2f(unsigned short u) {
    return __uint_as_float((unsigned)u << 16);
}

// ============ front kernel: embedding+xj0 ∥ filter tables ============
// Register-tiled 4x4 (bins x channels). Weights stream from global as
// per-lane float4; LDS is only read as wide broadcasts (float2 per 2 rows)
// -> ~2 LDS instr per 32 FMA instead of 17 per 16 (the R4 LDS-issue bound).
__global__ void __launch_bounds__(256) k_front(
        const int* __restrict__ an, const float* __restrict__ emb,
        const float* __restrict__ d1w, const float* __restrict__ d1b,
        const float* __restrict__ fw1, const float* __restrict__ fb1,
        const float* __restrict__ fw2, const float* __restrict__ fb2,
        float* __restrict__ x, unsigned short* __restrict__ xj,
        unsigned short* __restrict__ tab) {
    __shared__ __align__(16) float s_h[TB][132];    // table h / emb rows (row=528B, 16B-mult)
    __shared__ float s_rbf[TB][50];
    __shared__ int   s_an[32];
    int bid = blockIdx.x, t = threadIdx.x;
    int cq = t & 31, bg = t >> 5;                   // c = 4*cq+cc ; rows 4*bg+bb

    if (bid < EMB_BLOCKS) {
        // ---------- embedding gather + xj0 = x @ d1w[0] + d1b[0], 32 atoms ----------
        int i0 = bid * 32;
        if (t < 32) s_an[t] = an[i0 + t];
        __syncthreads();
        for (int idx = t; idx < 32 * HIDDEN; idx += 256) {
            int a = idx >> 7, c = idx & 127;
            float v = emb[(size_t)s_an[a] * HIDDEN + c];
            s_h[a][c] = v;
            x[(size_t)(i0 + a) * HIDDEN + c] = v;
        }
        __syncthreads();
        float o[4][4];
        float4 bv = *(const float4*)(d1b + 4 * cq);
        float bva[4] = { bv.x, bv.y, bv.z, bv.w };
        #pragma unroll
        for (int aa = 0; aa < 4; aa++)
            #pragma unroll
            for (int cc = 0; cc < 4; cc++) o[aa][cc] = bva[cc];
        #pragma unroll 4
        for (int h = 0; h < HIDDEN; h += 2) {
            float4 wA = *(const float4*)(d1w + (size_t)h * FILTERS + 4 * cq);
            float4 wB = *(const float4*)(d1w + (size_t)(h + 1) * FILTERS + 4 * cq);
            float wa[4] = { wA.x, wA.y, wA.z, wA.w };
            float wb[4] = { wB.x, wB.y, wB.z, wB.w };
            #pragma unroll
            for (int aa = 0; aa < 4; aa++) {
                float2 hp = *(const float2*)(&s_h[4 * bg + aa][h]);   // broadcast b64
                #pragma unroll
                for (int cc = 0; cc < 4; cc++) {
                    o[aa][cc] = fmaf(hp.x, wa[cc], o[aa][cc]);
                    o[aa][cc] = fmaf(hp.y, wb[cc], o[aa][cc]);
                }
            }
        }
        #pragma unroll
        for (int aa = 0; aa < 4; aa++) {
            int i = i0 + 4 * bg + aa;
            #pragma unroll
            for (int cp = 0; cp < 2; cp++) {
                unsigned int pk = (unsigned)f2bf(o[aa][2 * cp]) |
                                  ((unsigned)f2bf(o[aa][2 * cp + 1]) << 16);
                *(unsigned int*)(xj + (size_t)i * FILTERS + 4 * cq + 2 * cp) = pk;
            }
        }
    } else {
        // ---------- filter table: 32 bins/block, 4x4 register tiles ----------
        int tb = bid - EMB_BLOCKS;
        int l  = tb / TBLK, bx = tb % TBLK;
        int bin0 = bx * TB;
        const float* w1g = fw1 + (size_t)l * NUM_RBF * FILTERS;
        const float* w2g = fw2 + (size_t)l * FILTERS * FILTERS;
        for (int idx = t; idx < TB * NUM_RBF; idx += 256) {
            int b = idx / NUM_RBF, r = idx - b * NUM_RBF;
            float dd = (bin0 + b) * (CUTOFF / (float)KBINS);
            float cr = r * (CUTOFF / (float)(NUM_RBF - 1));
            float xx = dd - cr;
            s_rbf[b][r] = expf(-xx * xx * 12.5f);     // 1/(2*w^2), w = 0.2
        }
        __syncthreads();
        float hreg[4][4];
        float4 b1v = *(const float4*)(fb1 + (size_t)l * FILTERS + 4 * cq);
        float b1a[4] = { b1v.x, b1v.y, b1v.z, b1v.w };
        #pragma unroll
        for (int bb = 0; bb < 4; bb++)
            #pragma unroll
            for (int cc = 0; cc < 4; cc++) hreg[bb][cc] = b1a[cc];
        #pragma unroll 2
        for (int r = 0; r < NUM_RBF; r++) {
            float4 w = *(const float4*)(w1g + (size_t)r * FILTERS + 4 * cq);
            float wa[4] = { w.x, w.y, w.z, w.w };
            #pragma unroll
            for (int bb = 0; bb < 4; bb++) {
                float rb = s_rbf[4 * bg + bb][r];                     // broadcast b32
                #pragma unroll
                for (int cc = 0; cc < 4; cc++) hreg[bb][cc] = fmaf(rb, wa[cc], hreg[bb][cc]);
            }
        }
        #pragma unroll
        for (int bb = 0; bb < 4; bb++) {
            float4 sv;
            sv.x = hreg[bb][0] / (1.f + expf(-hreg[bb][0]));
            sv.y = hreg[bb][1] / (1.f + expf(-hreg[bb][1]));
            sv.z = hreg[bb][2] / (1.f + expf(-hreg[bb][2]));
            sv.w = hreg[bb][3] / (1.f + expf(-hreg[bb][3]));
            *(float4*)(&s_h[4 * bg + bb][4 * cq]) = sv;               // b128 write
        }
        __syncthreads();
        float o[4][4];
        float4 b2v = *(const float4*)(fb2 + (size_t)l * FILTERS + 4 * cq);
        float b2a[4] = { b2v.x, b2v.y, b2v.z, b2v.w };
        #pragma unroll
        for (int bb = 0; bb < 4; bb++)
            #pragma unroll
            for (int cc = 0; cc < 4; cc++) o[bb][cc] = b2a[cc];
        #pragma unroll 4
        for (int hh = 0; hh < FILTERS; hh += 2) {
            float4 wA = *(const float4*)(w2g + (size_t)hh * FILTERS + 4 * cq);
            float4 wB = *(const float4*)(w2g + (size_t)(hh + 1) * FILTERS + 4 * cq);
            float wa[4] = { wA.x, wA.y, wA.z, wA.w };
            float wb[4] = { wB.x, wB.y, wB.z, wB.w };
            #pragma unroll
            for (int bb = 0; bb < 4; bb++) {
                float2 hp = *(const float2*)(&s_h[4 * bg + bb][hh]);  // broadcast b64
                #pragma unroll
                for (int cc = 0; cc < 4; cc++) {
                    o[bb][cc] = fmaf(hp.x, wa[cc], o[bb][cc]);
                    o[bb][cc] = fmaf(hp.y, wb[cc], o[bb][cc]);
                }
            }
        }
        size_t base = (size_t)l * PROWS * FILTERS * 2;
        #pragma unroll
        for (int bb = 0; bb < 4; bb++) {
            int bin = bin0 + 4 * bg + bb;
            float dd = bin * (CUTOFF / (float)KBINS);
            float env = (bin >= KBINS) ? 0.f
                      : 0.5f * (cosf(dd * (3.14159265358979f / CUTOFF)) + 1.f);
            #pragma unroll
            for (int cc = 0; cc < 4; cc++) {
                int c = 4 * cq + cc;
                unsigned short pb = f2bf(o[bb][cc] * env);
                if (bin <= KBINS)                 tab[base + ((size_t)bin * FILTERS + c) * 2 + 0] = pb;
                if (bin >= 1 && bin <= KBINS + 1) tab[base + ((size_t)(bin - 1) * FILTERS + c) * 2 + 1] = pb;
            }
        }
    }
}

// ======== fused layer: (kw build for l=0) + agg + x update + next xj; one j per block ========
template<int FIRST, int LAST>
__global__ void __launch_bounds__(512) k_layer(const float* __restrict__ pos,
        float2* __restrict__ kw, const unsigned int* __restrict__ tab,
        const unsigned short* __restrict__ xj_in, float* __restrict__ x,
        const float* __restrict__ w2, const float* __restrict__ b2,
        const float* __restrict__ w1n, const float* __restrict__ b1n,
        unsigned short* __restrict__ xj_out) {
    int j = blockIdx.x;
    int t = threadIdx.x, f = t & 127, q = t >> 7;    // q in 0..3: i-quarter
    __shared__ float2 s_kw[N_ATOMS];
    __shared__ float  s_red[4][FILTERS];
    __shared__ float  s_agg[FILTERS];
    __shared__ float  s_xn[HIDDEN];
    __shared__ float  s_pos[FIRST ? N_ATOMS * 3 : 1];
    if (FIRST) {
        for (int idx = t; idx < N_ATOMS * 3; idx += 512) s_pos[idx] = pos[idx];
        __syncthreads();
        float pjx = s_pos[j*3+0], pjy = s_pos[j*3+1], pjz = s_pos[j*3+2];
        float dx = s_pos[t*3+0] - pjx;
        float dy = s_pos[t*3+1] - pjy;
        float dz = s_pos[t*3+2] - pjz;
        float d  = sqrtf(dx*dx + dy*dy + dz*dz);
        int   k; float w;
        if (t == j || d >= CUTOFF) { k = KBINS; w = 0.f; }   // all-zero pair row
        else {
            float tt = d * ((float)KBINS / CUTOFF);
            k = (int)tt;
            if (k > KBINS - 1) k = KBINS - 1;
            w = tt - (float)k;
        }
        float2 kv = make_float2(w, __int_as_float(k));
        s_kw[t] = kv;
        kw[(size_t)j * N_ATOMS + t] = kv;
        __syncthreads();
    } else {
        s_kw[t] = kw[(size_t)j * N_ATOMS + t];
        __syncthreads();
    }
    // ---- aggregation: each quarter sums 128 source atoms, 4 accumulators ----
    float acc0 = 0.f, acc1 = 0.f, acc2 = 0.f, acc3 = 0.f;
    int i0 = q * 128;
    #pragma unroll 2
    for (int ii = 0; ii < 128; ii += 4) {
        float2 kv0 = s_kw[i0 + ii];
        float2 kv1 = s_kw[i0 + ii + 1];
        float2 kv2 = s_kw[i0 + ii + 2];
        float2 kv3 = s_kw[i0 + ii + 3];
        unsigned int p0 = tab[(size_t)__float_as_int(kv0.y) * FILTERS + f];
        unsigned int p1 = tab[(size_t)__float_as_int(kv1.y) * FILTERS + f];
        unsigned int p2 = tab[(size_t)__float_as_int(kv2.y) * FILTERS + f];
        unsigned int p3 = tab[(size_t)__float_as_int(kv3.y) * FILTERS + f];
        float xv0 = bf2f(xj_in[(size_t)(i0 + ii    ) * FILTERS + f]);
        float xv1 = bf2f(xj_in[(size_t)(i0 + ii + 1) * FILTERS + f]);
        float xv2 = bf2f(xj_in[(size_t)(i0 + ii + 2) * FILTERS + f]);
        float xv3 = bf2f(xj_in[(size_t)(i0 + ii + 3) * FILTERS + f]);
        float lo0 = __uint_as_float(p0 << 16), hi0 = __uint_as_float(p0 & 0xffff0000u);
        float lo1 = __uint_as_float(p1 << 16), hi1 = __uint_as_float(p1 & 0xffff0000u);
        float lo2 = __uint_as_float(p2 << 16), hi2 = __uint_as_float(p2 & 0xffff0000u);
        float lo3 = __uint_as_float(p3 << 16), hi3 = __uint_as_float(p3 & 0xffff0000u);
        acc0 = fmaf(xv0, fmaf(kv0.x, hi0 - lo0, lo0), acc0);
        acc1 = fmaf(xv1, fmaf(kv1.x, hi1 - lo1, lo1), acc1);
        acc2 = fmaf(xv2, fmaf(kv2.x, hi2 - lo2, lo2), acc2);
        acc3 = fmaf(xv3, fmaf(kv3.x, hi3 - lo3, lo3), acc3);
    }
    s_red[q][f] = (acc0 + acc1) + (acc2 + acc3);
    __syncthreads();
    if (q == 0) s_agg[f] = s_red[0][f] + s_red[1][f] + s_red[2][f] + s_red[3][f];
    __syncthreads();
    // ---- x update: split the 128-term dot over quarters (32 each) ----
    float v = 0.f;
    int ff0 = q * 32;
    #pragma unroll 8
    for (int ff = ff0; ff < ff0 + 32; ff++) v = fmaf(s_agg[ff], w2[ff*HIDDEN + f], v);
    s_red[q][f] = v;
    __syncthreads();
    if (q == 0) {
        float xnew = x[j*HIDDEN + f] + b2[f] + s_red[0][f] + s_red[1][f] + s_red[2][f] + s_red[3][f];
        x[j*HIDDEN + f] = xnew;
        s_xn[f] = xnew;
    }
    __syncthreads();
    if (!LAST) {
        float a2 = 0.f;
        int h0 = q * 32;
        #pragma unroll 8
        for (int hh = h0; hh < h0 + 32; hh++) a2 = fmaf(s_xn[hh], w1n[hh*FILTERS + f], a2);
        s_red[q][f] = a2;
        __syncthreads();
        if (q == 0) xj_out[(size_t)j*FILTERS + f] =
            f2bf(b1n[f] + s_red[0][f] + s_red[1][f] + s_red[2][f] + s_red[3][f]);
    }
}

// ============ molecule pool + output MLP (binary search on sorted batch) ============
__device__ __forceinline__ int lbound(const int* __restrict__ b, int n, int v) {
    int lo = 0, hi = n;
    while (lo < hi) { int mid = (lo + hi) >> 1; if (b[mid] < v) lo = mid + 1; else hi = mid; }
    return lo;
}

__global__ void __launch_bounds__(128) k_pool(const float* __restrict__ x,
        const int* __restrict__ batch, const float* __restrict__ ow1,
        const float* __restrict__ ob1, const float* __restrict__ ow2,
        const float* __restrict__ ob2, float* __restrict__ out) {
    int m = blockIdx.x, t = threadIdx.x;
    int lo = lbound(batch, N_ATOMS, m);
    int hi = lbound(batch, N_ATOMS, m + 1);
    float s = 0.f;
    for (int i = lo; i < hi; i++) s += x[i*HIDDEN + t];
    int cnt = hi - lo;
    float mol = s / (float)(cnt > 0 ? cnt : 1);
    __shared__ float s_mol[HIDDEN];
    __shared__ float s_h[HIDDEN/2];
    s_mol[t] = mol;
    __syncthreads();
    if (t < HIDDEN/2) {
        float a = ob1[t];
        for (int h = 0; h < HIDDEN; h++) a = fmaf(s_mol[h], ow1[h*(HIDDEN/2) + t], a);
        s_h[t] = a / (1.f + expf(-a));
    }
    __syncthreads();
    if (t == 0) {
        float a = ob2[0];
        for (int h = 0; h < HIDDEN/2; h++) a = fmaf(s_h[h], ow2[h], a);
        out[m] = a;
    }
}

extern "C" void kernel_launch(void* const* d_in, const int* in_sizes, int n_in,
                              void* d_out, int out_size, void* d_ws, size_t ws_size,
                              hipStream_t stream) {
    const int*   an    = (const int*)  d_in[0];
    const float* pos   = (const float*)d_in[1];
    const int*   batch = (const int*)  d_in[2];
    const float* emb   = (const float*)d_in[3];
    const float* fw1   = (const float*)d_in[4];
    const float* fb1   = (const float*)d_in[5];
    const float* fw2   = (const float*)d_in[6];
    const float* fb2   = (const float*)d_in[7];
    const float* d1w   = (const float*)d_in[8];
    const float* d1b   = (const float*)d_in[9];
    const float* d2w   = (const float*)d_in[10];
    const float* d2b   = (const float*)d_in[11];
    const float* ow1   = (const float*)d_in[12];
    const float* ob1   = (const float*)d_in[13];
    const float* ow2   = (const float*)d_in[14];
    const float* ob2   = (const float*)d_in[15];
    float* out = (float*)d_out;

    float*          ws   = (float*)d_ws;
    float2*         kw   = (float2*)ws;                                    // 2 MB
    float*          x    = (float*)(kw + (size_t)N_ATOMS * N_ATOMS);       // 256 KB
    unsigned short* xjA  = (unsigned short*)(x + N_ATOMS * HIDDEN);        // 128 KB
    unsigned short* xjB  = xjA + (size_t)N_ATOMS * FILTERS;                // 128 KB
    unsigned short* tab  = xjB + (size_t)N_ATOMS * FILTERS;                // 1.575 MB

    k_front<<<EMB_BLOCKS + N_LAYERS * TBLK, 256, 0, stream>>>(
        an, emb, d1w, d1b, fw1, fb1, fw2, fb2, x, xjA, tab);

    const unsigned int* t0 = (const unsigned int*)(tab + (size_t)0 * PROWS * FILTERS * 2);
    const unsigned int* t1 = (const unsigned int*)(tab + (size_t)1 * PROWS * FILTERS * 2);
    const unsigned int* t2 = (const unsigned int*)(tab + (size_t)2 * PROWS * FILTERS * 2);

    k_layer<1,0><<<N_ATOMS, 512, 0, stream>>>(pos, kw, t0, xjA, x,
        d2w + (size_t)0*FILTERS*HIDDEN, d2b + (size_t)0*HIDDEN,
        d1w + (size_t)1*HIDDEN*FILTERS, d1b + (size_t)1*FILTERS, xjB);
    k_layer<0,0><<<N_ATOMS, 512, 0, stream>>>(pos, kw, t1, xjB, x,
        d2w + (size_t)1*FILTERS*HIDDEN, d2b + (size_t)1*HIDDEN,
        d1w + (size_t)2*HIDDEN*FILTERS, d1b + (size_t)2*FILTERS, xjA);
    k_layer<0,1><<<N_ATOMS, 512, 0, stream>>>(pos, kw, t2, xjA, x,
        d2w + (size_t)2*FILTERS*HIDDEN, d2b + (size_t)2*HIDDEN,
        d1w, d1b, xjB);

    k_pool<<<N_MOL, 128, 0, stream>>>(x, batch, ow1, ob1, ow2, ob2, out);
}